// Round 12
// baseline (275.707 us; speedup 1.0000x reference)
//
#include <hip/hip_runtime.h>
#include <hip/hip_fp8.h>
#include <math.h>

#define NN   100000
#define NE   1600000
#define DIN  128
#define DH   64
#define DOUT 40
#define BN_EPS 1e-5f
#define NBLK 98    // ceil(NN/1024)
#define KB   256   // buckets
#define BSZ  391   // nodes per bucket (256*391 = 100096 >= NN)
#define PBLK 256   // partition blocks
#define PE   6250  // NE / PBLK exact
#define N2   (KB * PBLK)  // 65536
#define NB2  64    // N2 / 1024
#define GB2  782   // ceil(NN/128) -- 128 rows per GEMM block

typedef unsigned short ushort_t;
typedef unsigned int uint_t;
typedef unsigned char uchar_t;

__device__ __forceinline__ float bf2f(ushort_t v) {
  union { uint_t u; float f; } w;
  w.u = ((uint_t)v) << 16;
  return w.f;
}
__device__ __forceinline__ ushort_t f2bf(float f) {  // RNE
  union { float f; uint_t u; } w;
  w.f = f;
  uint_t u = w.u;
  u += 0x7fffu + ((u >> 16) & 1u);
  return (ushort_t)(u >> 16);
}
__device__ __forceinline__ uchar_t f2e4m3(float f) {
  __hip_fp8_e4m3 q(f);  // OCP e4m3fn, RNE + satfinite
  return (uchar_t)q.__x;
}
__device__ __forceinline__ float e4m32f(uchar_t b) {
  __hip_fp8_e4m3 q;
  q.__x = (__hip_fp8_storage_t)b;
  return (float)q;
}
__device__ __forceinline__ float uhi2f(uint_t u) {  // high bf16
  union { uint_t u; float f; } w;
  w.u = u & 0xffff0000u;
  return w.f;
}
__device__ __forceinline__ float ulo2f(uint_t u) {  // low bf16
  union { uint_t u; float f; } w;
  w.u = u << 16;
  return w.f;
}

// ---------------- pass A: per-block bucket histogram (+stats zero) ----------------
__global__ void __launch_bounds__(512) k_cnt(const int* __restrict__ dst,
                                             int* __restrict__ cntmat,
                                             float* __restrict__ stats) {
  __shared__ int h[KB];
  int t = threadIdx.x, blk = blockIdx.x;
  if (t < KB) h[t] = 0;
  if (blk == 0 && t < 128) stats[t] = 0.0f;
  __syncthreads();
  int base = blk * PE;
  for (int i = t; i < PE; i += 512) {
    int d = dst[base + i];
    atomicAdd(&h[d / BSZ], 1);  // const divide -> magic mul
  }
  __syncthreads();
  if (t < KB) cntmat[t * PBLK + blk] = h[t];
}

// ---------------- scan C/D: exclusive scan of cntmat (65536, bucket-major) ----------------
__global__ void __launch_bounds__(1024) k_scanC(const int* __restrict__ cntmat,
                                                int* __restrict__ cscan,
                                                int* __restrict__ ctot) {
  __shared__ int sh[1024];
  int t = threadIdx.x, b = blockIdx.x;
  int i = b * 1024 + t;  // exact: 64*1024 = 65536
  int v = cntmat[i];
  sh[t] = v;
  __syncthreads();
  for (int off = 1; off < 1024; off <<= 1) {
    int u = (t >= off) ? sh[t - off] : 0;
    __syncthreads();
    sh[t] += u;
    __syncthreads();
  }
  cscan[i] = sh[t] - v;
  if (t == 1023) ctot[b] = sh[t];
}

__global__ void __launch_bounds__(1024) k_scanD(int* __restrict__ cscan,
                                                const int* __restrict__ ctot) {
  __shared__ int sh[NB2];
  int t = threadIdx.x, b = blockIdx.x;
  if (t < NB2) sh[t] = ctot[t];
  __syncthreads();
  for (int off = 1; off < NB2; off <<= 1) {
    int u = (t >= off && t < NB2) ? sh[t - off] : 0;
    __syncthreads();
    if (t < NB2) sh[t] += u;
    __syncthreads();
  }
  if (b > 0) cscan[b * 1024 + t] += sh[b - 1];
}

// ---------------- pass C: scatter edges to deterministic bucket slots ----------------
// payload = (src << 9) | d_local   (src < 2^17, d_local < 391 < 2^9)
__global__ void __launch_bounds__(512) k_scat(const int* __restrict__ src,
                                              const int* __restrict__ dst,
                                              const int* __restrict__ cscan,
                                              uint_t* __restrict__ bpair) {
  __shared__ int cur[KB];
  int t = threadIdx.x, blk = blockIdx.x;
  if (t < KB) cur[t] = cscan[t * PBLK + blk];
  __syncthreads();
  int base = blk * PE;
  for (int i = t; i < PE; i += 512) {
    int e = base + i;
    int d = dst[e], s = src[e];
    int b = d / BSZ;
    int pos = atomicAdd(&cur[b], 1);
    bpair[pos] = ((uint_t)s << 9) | (uint_t)(d - b * BSZ);
  }
}

// ---------------- per-bucket count -> hist (coalesced, no global atomics) ----------------
__global__ void __launch_bounds__(512) k_count(const int* __restrict__ cscan,
                                               const uint_t* __restrict__ bpair,
                                               int* __restrict__ hist) {
  __shared__ int cnt[BSZ];
  int b = blockIdx.x, t = threadIdx.x;
  for (int i = t; i < BSZ; i += 512) cnt[i] = 0;
  __syncthreads();
  int start = cscan[b * PBLK];
  int end = (b + 1 < KB) ? cscan[(b + 1) * PBLK] : NE;
  for (int i = start + t; i < end; i += 512) atomicAdd(&cnt[bpair[i] & 511u], 1);
  __syncthreads();
  int nodebase = b * BSZ;
  for (int i = t; i < BSZ; i += 512) {
    int node = nodebase + i;
    if (node < NN) hist[node] = cnt[i];
  }
}

// ---------------- scan A: per-1024-block exclusive scan; fused dinv ----------------
__global__ void __launch_bounds__(1024) k_scanA(const int* __restrict__ hist,
                                                int* __restrict__ rowptr,
                                                int* __restrict__ btot,
                                                float* __restrict__ dinv) {
  __shared__ int sh[1024];
  int t = threadIdx.x, b = blockIdx.x;
  int i = b * 1024 + t;
  int v = (i < NN) ? hist[i] : 0;
  sh[t] = v;
  __syncthreads();
  for (int off = 1; off < 1024; off <<= 1) {
    int u = (t >= off) ? sh[t - off] : 0;
    __syncthreads();
    sh[t] += u;
    __syncthreads();
  }
  if (i < NN) {
    rowptr[i] = sh[t] - v;
    dinv[i] = rsqrtf(1.0f + (float)v);
  }
  if (t == 1023) btot[b] = sh[t];
}

// ---------------- scan B: add block offsets ----------------
__global__ void __launch_bounds__(1024) k_scanB(int* __restrict__ rowptr,
                                                const int* __restrict__ btot) {
  __shared__ int sh[128];
  int t = threadIdx.x, b = blockIdx.x;
  if (t < 128) sh[t] = (t < NBLK) ? btot[t] : 0;
  __syncthreads();
  for (int off = 1; off < 128; off <<= 1) {
    int u = (t >= off && t < 128) ? sh[t - off] : 0;
    __syncthreads();
    if (t < 128) sh[t] += u;
    __syncthreads();
  }
  int i = b * 1024 + t;
  if (i < NN && b > 0) rowptr[i] += sh[b - 1];
}

// ---------------- fill CSR from buckets (block-private window, LDS cursors) ----------------
__global__ void __launch_bounds__(512) k_fill2(const uint_t* __restrict__ bpair,
                                               const int* __restrict__ cscan,
                                               const int* __restrict__ rowptr,
                                               int* __restrict__ csr) {
  __shared__ int cur[BSZ];
  __shared__ int rp[BSZ];
  int b = blockIdx.x, t = threadIdx.x;
  int nodebase = b * BSZ;
  for (int i = t; i < BSZ; i += 512) {
    cur[i] = 0;
    int node = nodebase + i;
    rp[i] = (node < NN) ? rowptr[node] : 0;
  }
  __syncthreads();
  int start = cscan[b * PBLK];
  int end = (b + 1 < KB) ? cscan[(b + 1) * PBLK] : NE;
  for (int i = start + t; i < end; i += 512) {
    uint_t u = bpair[i];
    int dloc = (int)(u & 511u);
    int pos = rp[dloc] + atomicAdd(&cur[dloc], 1);
    csr[pos] = (int)(u >> 9);
  }
}

// ---------------- h1pre = (x0 @ W1) * dinv, stored bf16 ----------------
// 4 threads per row (16 ch each), 2 rows per thread, W1 staged in LDS.
__global__ void __launch_bounds__(256) k_gemm1(const float* __restrict__ X,
                                               const float* __restrict__ W,
                                               const float* __restrict__ dinv,
                                               ushort_t* __restrict__ Hb) {
  __shared__ float w[DIN * DH];  // 32 KB
  int t = threadIdx.x;
  {
    const float4* ws = (const float4*)W;
    float4* wd = (float4*)w;
#pragma unroll
    for (int i = 0; i < DIN * DH / 4 / 256; ++i) wd[t + i * 256] = ws[t + i * 256];
  }
  __syncthreads();
  int rr = t >> 2, q = t & 3;
  int row0 = blockIdx.x * 128 + rr;
  int row1 = row0 + 64;
  bool v0 = row0 < NN, v1 = row1 < NN;
  float acc0[16], acc1[16];
#pragma unroll
  for (int j = 0; j < 16; ++j) { acc0[j] = 0.0f; acc1[j] = 0.0f; }
  const float4* xr0 = (const float4*)(X + (size_t)row0 * DIN);
  const float4* xr1 = (const float4*)(X + (size_t)row1 * DIN);
  const float4 z4 = make_float4(0.f, 0.f, 0.f, 0.f);
  for (int k4 = 0; k4 < DIN / 4; ++k4) {
    float4 a = v0 ? xr0[k4] : z4;
    float4 b = v1 ? xr1[k4] : z4;
#pragma unroll
    for (int kk = 0; kk < 4; ++kk) {
      const float* wr = w + (k4 * 4 + kk) * DH + q * 16;
      float xa = (&a.x)[kk], xb = (&b.x)[kk];
#pragma unroll
      for (int j = 0; j < 16; ++j) {
        acc0[j] = fmaf(xa, wr[j], acc0[j]);
        acc1[j] = fmaf(xb, wr[j], acc1[j]);
      }
    }
  }
  if (v0) {
    float di = dinv[row0];
    uint_t pk[8];
#pragma unroll
    for (int j = 0; j < 8; ++j)
      pk[j] = (uint_t)f2bf(acc0[2 * j] * di) | ((uint_t)f2bf(acc0[2 * j + 1] * di) << 16);
    uint4* o = (uint4*)(Hb + (size_t)row0 * DH + q * 16);
    o[0] = make_uint4(pk[0], pk[1], pk[2], pk[3]);
    o[1] = make_uint4(pk[4], pk[5], pk[6], pk[7]);
  }
  if (v1) {
    float di = dinv[row1];
    uint_t pk[8];
#pragma unroll
    for (int j = 0; j < 8; ++j)
      pk[j] = (uint_t)f2bf(acc1[2 * j] * di) | ((uint_t)f2bf(acc1[2 * j + 1] * di) << 16);
    uint4* o = (uint4*)(Hb + (size_t)row1 * DH + q * 16);
    o[0] = make_uint4(pk[0], pk[1], pk[2], pk[3]);
    o[1] = make_uint4(pk[4], pk[5], pk[6], pk[7]);
  }
}

// ---- gather1 + BN stats: 8 edges per VMEM instr (8 lane-groups x uint4) ----
// lane = g*8 + r: group g handles edge k+g, lane loads channels r*8..r*8+7.
__global__ void __launch_bounds__(256) k_gather1(const int* __restrict__ csr,
                                                 const int* __restrict__ rowptr,
                                                 const int* __restrict__ cnt,
                                                 const float* __restrict__ dinv,
                                                 const ushort_t* __restrict__ Hb,
                                                 const float* __restrict__ bias,
                                                 float* __restrict__ Agg,
                                                 float* __restrict__ stats) {
  int lane = threadIdx.x & 63, w = threadIdx.x >> 6;
  int g = lane >> 3, r = lane & 7;
  int wid = blockIdx.x * 4 + w;
  int nw = gridDim.x * 4;
  // per-lane bias slice (only used by g==0 lanes)
  float bcv[8];
  {
    const float4* bp = (const float4*)(bias + r * 8);
    float4 b0 = bp[0], b1 = bp[1];
    bcv[0] = b0.x; bcv[1] = b0.y; bcv[2] = b0.z; bcv[3] = b0.w;
    bcv[4] = b1.x; bcv[5] = b1.y; bcv[6] = b1.z; bcv[7] = b1.w;
  }
  float s1[8], s2[8];
#pragma unroll
  for (int j = 0; j < 8; ++j) { s1[j] = 0.0f; s2[j] = 0.0f; }
  for (int d = wid; d < NN; d += nw) {
    int st = __builtin_amdgcn_readfirstlane(rowptr[d]);
    int n  = __builtin_amdgcn_readfirstlane(cnt[d]);
    float acc[8];
#pragma unroll
    for (int j = 0; j < 8; ++j) acc[j] = 0.0f;
    const int* cs = csr + st;
    int k = 0;
    for (; k + 16 <= n; k += 16) {
      int ia = cs[k + g];
      int ib = cs[k + 8 + g];
      uint4 va = *(const uint4*)(Hb + (size_t)ia * DH + r * 8);
      uint4 vb = *(const uint4*)(Hb + (size_t)ib * DH + r * 8);
      acc[0] += ulo2f(va.x) + ulo2f(vb.x);
      acc[1] += uhi2f(va.x) + uhi2f(vb.x);
      acc[2] += ulo2f(va.y) + ulo2f(vb.y);
      acc[3] += uhi2f(va.y) + uhi2f(vb.y);
      acc[4] += ulo2f(va.z) + ulo2f(vb.z);
      acc[5] += uhi2f(va.z) + uhi2f(vb.z);
      acc[6] += ulo2f(va.w) + ulo2f(vb.w);
      acc[7] += uhi2f(va.w) + uhi2f(vb.w);
    }
    for (; k < n; k += 8) {
      if (k + g < n) {
        int ia = cs[k + g];
        uint4 va = *(const uint4*)(Hb + (size_t)ia * DH + r * 8);
        acc[0] += ulo2f(va.x);
        acc[1] += uhi2f(va.x);
        acc[2] += ulo2f(va.y);
        acc[3] += uhi2f(va.y);
        acc[4] += ulo2f(va.z);
        acc[5] += uhi2f(va.z);
        acc[6] += ulo2f(va.w);
        acc[7] += uhi2f(va.w);
      }
    }
    // reduce over g (strides 8,16,32)
#pragma unroll
    for (int j = 0; j < 8; ++j) {
      float v = acc[j];
      v += __shfl_xor(v, 8);
      v += __shfl_xor(v, 16);
      v += __shfl_xor(v, 32);
      acc[j] = v;
    }
    if (g == 0) {
      // self term + scale + bias; write + stats
      uint4 sv = *(const uint4*)(Hb + (size_t)d * DH + r * 8);
      float se[8];
      se[0] = ulo2f(sv.x); se[1] = uhi2f(sv.x);
      se[2] = ulo2f(sv.y); se[3] = uhi2f(sv.y);
      se[4] = ulo2f(sv.z); se[5] = uhi2f(sv.z);
      se[6] = ulo2f(sv.w); se[7] = uhi2f(sv.w);
      float wd = dinv[d];
      float v[8];
#pragma unroll
      for (int j = 0; j < 8; ++j) {
        v[j] = fmaf(acc[j] + se[j], wd, bcv[j]);
        s1[j] += v[j];
        s2[j] += v[j] * v[j];
      }
      float4* ao = (float4*)(Agg + (size_t)d * DH + r * 8);
      ao[0] = make_float4(v[0], v[1], v[2], v[3]);
      ao[1] = make_float4(v[4], v[5], v[6], v[7]);
    }
  }
  // block-level stats reduction
  __shared__ float sred[2][4][64];
  if (g == 0) {
#pragma unroll
    for (int j = 0; j < 8; ++j) {
      sred[0][w][r * 8 + j] = s1[j];
      sred[1][w][r * 8 + j] = s2[j];
    }
  }
  __syncthreads();
  int t = threadIdx.x;
  if (t < 64) {
    float a = sred[0][0][t] + sred[0][1][t] + sred[0][2][t] + sred[0][3][t];
    float b = sred[1][0][t] + sred[1][1][t] + sred[1][2][t] + sred[1][3][t];
    atomicAdd(&stats[t], a);
    atomicAdd(&stats[64 + t], b);
  }
}

// -------- finalize BN: scale/shift; cvec = bl + b2@Wl_bot; W2b = W2 @ Wl_bot --------
__global__ void __launch_bounds__(256) k_bnfinal(const float* __restrict__ stats,
                                                 const float* __restrict__ g,
                                                 const float* __restrict__ be,
                                                 const float* __restrict__ b2,
                                                 const float* __restrict__ Wl,
                                                 const float* __restrict__ bl,
                                                 const float* __restrict__ W2,
                                                 float* __restrict__ scsh,
                                                 float* __restrict__ cvec,
                                                 float* __restrict__ W2b) {
  int t = threadIdx.x;
  if (t < 64) {
    float mean = stats[t] * (1.0f / NN);
    float var = stats[64 + t] * (1.0f / NN) - mean * mean;
    float sc = g[t] * rsqrtf(var + BN_EPS);
    scsh[t] = sc;
    scsh[64 + t] = be[t] - mean * sc;
  }
  if (t < DOUT) {
    float s = bl[t];
    for (int k = 0; k < DH; ++k) s = fmaf(b2[k], Wl[(DH + k) * DOUT + t], s);
    cvec[t] = s;
  }
  // W2b[k][j] = sum_m W2[k][m] * Wl[(64+m)*40 + j]; thread t: k = t>>2, j-block = (t&3)*10
  {
    int k = t >> 2, jq = (t & 3) * 10;
    float a[10];
#pragma unroll
    for (int j = 0; j < 10; ++j) a[j] = 0.0f;
    for (int m = 0; m < DH; ++m) {
      float wv = W2[k * DH + m];
      const float* wl = Wl + (DH + m) * DOUT + jq;
#pragma unroll
      for (int j = 0; j < 10; ++j) a[j] = fmaf(wv, wl[j], a[j]);
    }
#pragma unroll
    for (int j = 0; j < 10; ++j) W2b[k * DOUT + jq + j] = a[j];
  }
}

// ---- x1 = relu(bn(agg1)); y1 = x1@Wl_top + cvec; z = fp8(dinv * (x1@W2b)) ----
// Z rows padded to 64 B (channels 40..63 zero).
__global__ void __launch_bounds__(256) k_bngemm2(const float* __restrict__ Agg1,
                                                 const float* __restrict__ scsh,
                                                 const float* __restrict__ dinv,
                                                 const float* __restrict__ Wl,
                                                 const float* __restrict__ W2b,
                                                 const float* __restrict__ cvec,
                                                 float* __restrict__ Y1,
                                                 uchar_t* __restrict__ Z) {
  __shared__ float wlt[DH * DOUT];  // 10 KB  (Wl rows 0..63)
  __shared__ float wzb[DH * DOUT];  // 10 KB  (W2 @ Wl_bot)
  __shared__ float ss[128];
  __shared__ float cvs[DOUT];
  int t = threadIdx.x;
  {
    const float4* s4 = (const float4*)Wl;
    float4* d4 = (float4*)wlt;
    for (int i = t; i < DH * DOUT / 4; i += 256) d4[i] = s4[i];
    s4 = (const float4*)W2b;
    d4 = (float4*)wzb;
    for (int i = t; i < DH * DOUT / 4; i += 256) d4[i] = s4[i];
    if (t < 128) ss[t] = scsh[t];
    if (t < DOUT) cvs[t] = cvec[t];
  }
  __syncthreads();
  int rr = t >> 2, q = t & 3;
  int row0 = blockIdx.x * 128 + rr;
  int row1 = row0 + 64;
  bool v0 = row0 < NN, v1 = row1 < NN;
  float y0[10], y1a[10], z0[10], z1[10];
#pragma unroll
  for (int j = 0; j < 10; ++j) {
    float cv = cvs[q * 10 + j];
    y0[j] = cv; y1a[j] = cv; z0[j] = 0.0f; z1[j] = 0.0f;
  }
  const float4* ar0 = (const float4*)(Agg1 + (size_t)row0 * DH);
  const float4* ar1 = (const float4*)(Agg1 + (size_t)row1 * DH);
  const float4 zz = make_float4(0.f, 0.f, 0.f, 0.f);
  for (int k4 = 0; k4 < DH / 4; ++k4) {
    float4 a = v0 ? ar0[k4] : zz;
    float4 b = v1 ? ar1[k4] : zz;
#pragma unroll
    for (int kk = 0; kk < 4; ++kk) {
      int k = k4 * 4 + kk;
      float sck = ss[k], shk = ss[64 + k];
      float xa = fmaxf(fmaf((&a.x)[kk], sck, shk), 0.0f);
      float xb = fmaxf(fmaf((&b.x)[kk], sck, shk), 0.0f);
      const float* wt = wlt + k * DOUT + q * 10;
      const float* wb = wzb + k * DOUT + q * 10;
#pragma unroll
      for (int j = 0; j < 10; ++j) {
        y0[j] = fmaf(xa, wt[j], y0[j]);
        y1a[j] = fmaf(xb, wt[j], y1a[j]);
        z0[j] = fmaf(xa, wb[j], z0[j]);
        z1[j] = fmaf(xb, wb[j], z1[j]);
      }
    }
  }
  if (v0) {
    float2* yo = (float2*)(Y1 + (size_t)row0 * DOUT + q * 10);
#pragma unroll
    for (int p = 0; p < 5; ++p) yo[p] = make_float2(y0[2 * p], y0[2 * p + 1]);
    float di = dinv[row0];
    ushort_t* zp = (ushort_t*)(Z + (size_t)row0 * 64 + q * 10);
#pragma unroll
    for (int p = 0; p < 5; ++p)
      zp[p] = (ushort_t)f2e4m3(z0[2 * p] * di) | ((ushort_t)f2e4m3(z0[2 * p + 1] * di) << 8);
    if (q < 3) *(uint2*)(Z + (size_t)row0 * 64 + 40 + q * 8) = make_uint2(0u, 0u);
  }
  if (v1) {
    float2* yo = (float2*)(Y1 + (size_t)row1 * DOUT + q * 10);
#pragma unroll
    for (int p = 0; p < 5; ++p) yo[p] = make_float2(y1a[2 * p], y1a[2 * p + 1]);
    float di = dinv[row1];
    ushort_t* zp = (ushort_t*)(Z + (size_t)row1 * 64 + q * 10);
#pragma unroll
    for (int p = 0; p < 5; ++p)
      zp[p] = (ushort_t)f2e4m3(z1[2 * p] * di) | ((ushort_t)f2e4m3(z1[2 * p + 1] * di) << 8);
    if (q < 3) *(uint2*)(Z + (size_t)row1 * 64 + 40 + q * 8) = make_uint2(0u, 0u);
  }
}

// ---- gather2 + log_softmax: 8 edges per VMEM instr (8 lane-groups x uint2 fp8) ----
__global__ void __launch_bounds__(256) k_g2final(const int* __restrict__ csr,
                                                 const int* __restrict__ rowptr,
                                                 const int* __restrict__ cnt,
                                                 const float* __restrict__ dinv,
                                                 const uchar_t* __restrict__ Z,
                                                 const float* __restrict__ Y1,
                                                 float* __restrict__ Out) {
  int lane = threadIdx.x & 63, w = threadIdx.x >> 6;
  int g = lane >> 3, r = lane & 7;
  int d = blockIdx.x * 4 + w;  // grid exact: 25000*4 = NN
  int st = __builtin_amdgcn_readfirstlane(rowptr[d]);
  int n  = __builtin_amdgcn_readfirstlane(cnt[d]);
  float acc[8];
#pragma unroll
  for (int j = 0; j < 8; ++j) acc[j] = 0.0f;
  const int* cs = csr + st;
  int k = 0;
  for (; k + 16 <= n; k += 16) {
    int ia = cs[k + g];
    int ib = cs[k + 8 + g];
    uint2 va = *(const uint2*)(Z + (size_t)ia * 64 + r * 8);
    uint2 vb = *(const uint2*)(Z + (size_t)ib * 64 + r * 8);
#pragma unroll
    for (int b = 0; b < 4; ++b) {
      acc[b] += e4m32f((uchar_t)(va.x >> (8 * b))) + e4m32f((uchar_t)(vb.x >> (8 * b)));
      acc[4 + b] += e4m32f((uchar_t)(va.y >> (8 * b))) + e4m32f((uchar_t)(vb.y >> (8 * b)));
    }
  }
  for (; k < n; k += 8) {
    if (k + g < n) {
      int ia = cs[k + g];
      uint2 va = *(const uint2*)(Z + (size_t)ia * 64 + r * 8);
#pragma unroll
      for (int b = 0; b < 4; ++b) {
        acc[b] += e4m32f((uchar_t)(va.x >> (8 * b)));
        acc[4 + b] += e4m32f((uchar_t)(va.y >> (8 * b)));
      }
    }
  }
  // reduce over g
#pragma unroll
  for (int j = 0; j < 8; ++j) {
    float v = acc[j];
    v += __shfl_xor(v, 8);
    v += __shfl_xor(v, 16);
    v += __shfl_xor(v, 32);
    acc[j] = v;
  }
  // self term (pad channels are zero)
  {
    uint2 sv = *(const uint2*)(Z + (size_t)d * 64 + r * 8);
#pragma unroll
    for (int b = 0; b < 4; ++b) {
      acc[b] += e4m32f((uchar_t)(sv.x >> (8 * b)));
      acc[4 + b] += e4m32f((uchar_t)(sv.y >> (8 * b)));
    }
  }
  float wd = dinv[d];
  float o[8];
  bool valid = r < 5;  // channels r*8..r*8+7 < 40
  if (valid) {
    const float4* yp = (const float4*)(Y1 + (size_t)d * DOUT + r * 8);
    float4 ya = yp[0], yb = yp[1];
    o[0] = ya.x + wd * acc[0]; o[1] = ya.y + wd * acc[1];
    o[2] = ya.z + wd * acc[2]; o[3] = ya.w + wd * acc[3];
    o[4] = yb.x + wd * acc[4]; o[5] = yb.y + wd * acc[5];
    o[6] = yb.z + wd * acc[6]; o[7] = yb.w + wd * acc[7];
  } else {
#pragma unroll
    for (int j = 0; j < 8; ++j) o[j] = -1e30f;
  }
  // softmax across the 40 valid channels: local 8-max then reduce over r (strides 1,2,4)
  float m = o[0];
#pragma unroll
  for (int j = 1; j < 8; ++j) m = fmaxf(m, o[j]);
  m = fmaxf(m, __shfl_xor(m, 1));
  m = fmaxf(m, __shfl_xor(m, 2));
  m = fmaxf(m, __shfl_xor(m, 4));
  float ls = 0.0f;
  if (valid) {
#pragma unroll
    for (int j = 0; j < 8; ++j) ls += __expf(o[j] - m);
  }
  ls += __shfl_xor(ls, 1);
  ls += __shfl_xor(ls, 2);
  ls += __shfl_xor(ls, 4);
  float lse = m + __logf(ls);
  if (g == 0 && valid) {
    float4* op = (float4*)(Out + (size_t)d * DOUT + r * 8);
    op[0] = make_float4(o[0] - lse, o[1] - lse, o[2] - lse, o[3] - lse);
    op[1] = make_float4(o[4] - lse, o[5] - lse, o[6] - lse, o[7] - lse);
  }
}

extern "C" void kernel_launch(void* const* d_in, const int* in_sizes, int n_in,
                              void* d_out, int out_size, void* d_ws, size_t ws_size,
                              hipStream_t stream) {
  const float* x0  = (const float*)d_in[0];
  const int*   ei  = (const int*)d_in[1];
  const float* W1  = (const float*)d_in[2];
  const float* b1  = (const float*)d_in[3];
  const float* g1  = (const float*)d_in[4];
  const float* be1 = (const float*)d_in[5];
  const float* W2  = (const float*)d_in[6];
  const float* b2  = (const float*)d_in[7];
  const float* Wl  = (const float*)d_in[8];
  const float* bl  = (const float*)d_in[9];
  float* out = (float*)d_out;

  const int* src = ei;
  const int* dst = ei + NE;

  // workspace layout (16B alignment preserved at each buffer)
  char* w8 = (char*)d_ws;
  int*   hist   = (int*)w8;                        // NN
  int*   rowptr = hist + NN;                       // NN (+64 pad)
  int*   btot   = rowptr + NN + 64;                // 128
  float* stats  = (float*)(btot + 128);            // 128
  float* scsh   = stats + 128;                     // 128
  float* cvec   = scsh + 128;                      // 64
  float* w2b    = cvec + 64;                       // 2560 (W2 @ Wl_bot)
  float* dinv   = w2b + 2560;                      // NN (+64 pad)
  int*   cntmat = (int*)(dinv + NN + 64);          // 65536
  int*   cscan  = cntmat + N2;                     // 65536
  int*   ctot   = cscan + N2;                      // 64 (+64 pad)
  uint_t* bpair = (uint_t*)(ctot + 128);           // NE u32 (6.4 MB)
  int*   csr    = (int*)(bpair + NE);              // NE (+64 pad)
  ushort_t* Hb  = (ushort_t*)(csr + NE + 64);      // NN*64 bf16 (h1pre)
  float* Agg1   = (float*)(Hb + (size_t)NN * DH);  // NN*64 f32 (agg1)
  float* Y1     = Agg1 + (size_t)NN * DH;          // NN*40 f32
  uchar_t* Z    = (uchar_t*)(Y1 + (size_t)NN * DOUT);  // NN*64 fp8 (padded rows)

  const int B = 256;
  int gP = NN / 4;             // 25000: 4 waves/block, 1 node/wave, exact

  k_cnt<<<PBLK, 512, 0, stream>>>(dst, cntmat, stats);
  k_scanC<<<NB2, 1024, 0, stream>>>(cntmat, cscan, ctot);
  k_scanD<<<NB2, 1024, 0, stream>>>(cscan, ctot);
  k_scat<<<PBLK, 512, 0, stream>>>(src, dst, cscan, bpair);
  k_count<<<KB, 512, 0, stream>>>(cscan, bpair, hist);
  k_scanA<<<NBLK, 1024, 0, stream>>>(hist, rowptr, btot, dinv);
  k_scanB<<<NBLK, 1024, 0, stream>>>(rowptr, btot);
  k_fill2<<<KB, 512, 0, stream>>>(bpair, cscan, rowptr, csr);

  k_gemm1<<<GB2, B, 0, stream>>>(x0, W1, dinv, Hb);
  k_gather1<<<2048, B, 0, stream>>>(csr, rowptr, hist, dinv, Hb, b1, Agg1, stats);
  k_bnfinal<<<1, 256, 0, stream>>>(stats, g1, be1, b2, Wl, bl, W2, scsh, cvec, w2b);

  k_bngemm2<<<GB2, B, 0, stream>>>(Agg1, scsh, dinv, Wl, w2b, cvec, Y1, Z);
  k_g2final<<<gP, B, 0, stream>>>(csr, rowptr, hist, dinv, Z, Y1, out);
}